// Round 1
// 233.800 us; speedup vs baseline: 1.0195x; 1.0195x over previous
//
#include <hip/hip_runtime.h>

typedef __bf16 bf16;
typedef __bf16 bf16x4 __attribute__((ext_vector_type(4)));
typedef __bf16 bf16x8 __attribute__((ext_vector_type(8)));
typedef float f32x4 __attribute__((ext_vector_type(4)));

#define LOG2E 1.44269504088896f

// async global->LDS, 16B per lane. LDS dest is wave-uniform base + lane*16
// (m104/m108): pass the lane-0 pointer; generic->AS(3) = low-32-bit truncation.
__device__ __forceinline__ void gl_lds16(const bf16* g, bf16* l) {
  __builtin_amdgcn_global_load_lds(
      reinterpret_cast<const __attribute__((address_space(1))) void*>((uintptr_t)g),
      reinterpret_cast<__attribute__((address_space(3))) void*>((uint32_t)(uintptr_t)l),
      16, 0, 0);
}

// ---------------- cast fp32 -> bf16 for weights + pm, and build RoPE cos/sin table ----------------
__global__ void cast3_kernel(const float* __restrict__ a, int na4, bf16* __restrict__ oa,
                             const float* __restrict__ b, int nb4, bf16* __restrict__ ob,
                             const float* __restrict__ c, int nc4, bf16* __restrict__ oc,
                             float2* __restrict__ tab, int nt) {
  int i = blockIdx.x * blockDim.x + threadIdx.x;
  if (i < na4 + nb4 + nc4) {
    const float* src; bf16* dst; int idx;
    if (i < na4)            { src = a; dst = oa; idx = i; }
    else if (i < na4 + nb4) { src = b; dst = ob; idx = i - na4; }
    else                    { src = c; dst = oc; idx = i - na4 - nb4; }
    float4 v = ((const float4*)src)[idx];
    bf16x4 o = { (bf16)v.x, (bf16)v.y, (bf16)v.z, (bf16)v.w };
    ((bf16x4*)dst)[idx] = o;
  } else {
    int idx = i - (na4 + nb4 + nc4);
    if (idx >= nt) return;
    int pos = idx >> 5, fi = idx & 31;
    float inv = exp2f((float)fi * -0.41524101186f);   // 10000^(-fi/32)
    float th = (float)pos * inv;
    float sn, cs;
    sincosf(th, &sn, &cs);
    tab[idx] = make_float2(cs, sn);
  }
}

// ---------------- RMSNorm: seq fp32 [8192][1024] -> x bf16 ----------------
__global__ __launch_bounds__(256) void rmsnorm_kernel(const float* __restrict__ seq,
                                                      const float* __restrict__ g,
                                                      bf16* __restrict__ xbf) {
  int row = blockIdx.x;
  int t = threadIdx.x;
  float4 x = ((const float4*)(seq + (size_t)row * 1024))[t];
  float ss = x.x*x.x + x.y*x.y + x.z*x.z + x.w*x.w;
  #pragma unroll
  for (int m = 32; m >= 1; m >>= 1) ss += __shfl_xor(ss, m, 64);
  __shared__ float red[4];
  if ((t & 63) == 0) red[t >> 6] = ss;
  __syncthreads();
  float tot = red[0] + red[1] + red[2] + red[3];
  float scale = rsqrtf(tot * (1.0f / 1024.0f) + 1.1920929e-07f);
  float4 gv = ((const float4*)g)[t];
  bf16x4 o = { (bf16)(x.x*scale*gv.x), (bf16)(x.y*scale*gv.y),
               (bf16)(x.z*scale*gv.z), (bf16)(x.w*scale*gv.w) };
  ((bf16x4*)(xbf + (size_t)row * 1024))[t] = o;
}

// ---------------- GEMM C[M,N] = A[M,K] * B[N,K]^T  (bf16 in, bf16/fp32 out) ----------------
// 128-tile m97-lineage kernel: kept for the output projection (N=1024 -> 512 blocks).
template<int OUTF>
__global__ __launch_bounds__(256) void gemm_bt_kernel(const bf16* __restrict__ A,
                                                      const bf16* __restrict__ B,
                                                      void* __restrict__ C,
                                                      int M, int N, int K) {
  __shared__ bf16 As[128 * 64];
  __shared__ bf16 Bs[128 * 64];
  int t = threadIdx.x;
  int lane = t & 63, wv = t >> 6;
  int m16 = lane & 15, quad = lane >> 4;
  int bn = blockIdx.x, bm = blockIdx.y;
  const bf16* Ab = A + (size_t)bm * 128 * K;
  const bf16* Bb = B + (size_t)bn * 128 * K;
  int wr = (wv >> 1) * 64, wc = (wv & 1) * 64;
  f32x4 acc[4][4] = {};
  for (int k0 = 0; k0 < K; k0 += 64) {
    #pragma unroll
    for (int i = 0; i < 4; i++) {
      int cb = i * 256 + wv * 64;          // wave-uniform chunk base (16B chunks)
      int s = cb + lane;
      int row = s >> 3, p = s & 7, g = p ^ (row & 7);
      gl_lds16(Ab + (size_t)row * K + k0 + g * 8, &As[cb * 8]);
      gl_lds16(Bb + (size_t)row * K + k0 + g * 8, &Bs[cb * 8]);
    }
    __syncthreads();   // implicit s_waitcnt vmcnt(0) drains the LDS-DMA
    #pragma unroll
    for (int kk = 0; kk < 2; kk++) {
      bf16x8 af[4], bfr[4];
      #pragma unroll
      for (int i = 0; i < 4; i++) {
        int row = wr + i * 16 + m16;
        int p = (kk * 4 + quad) ^ (row & 7);
        af[i] = *(const bf16x8*)(&As[row * 64 + p * 8]);
      }
      #pragma unroll
      for (int j = 0; j < 4; j++) {
        int row = wc + j * 16 + m16;
        int p = (kk * 4 + quad) ^ (row & 7);
        bfr[j] = *(const bf16x8*)(&Bs[row * 64 + p * 8]);
      }
      #pragma unroll
      for (int i = 0; i < 4; i++)
        #pragma unroll
        for (int j = 0; j < 4; j++)
          acc[i][j] = __builtin_amdgcn_mfma_f32_16x16x32_bf16(af[i], bfr[j], acc[i][j], 0, 0, 0);
    }
    __syncthreads();
  }
  #pragma unroll
  for (int i = 0; i < 4; i++)
    #pragma unroll
    for (int j = 0; j < 4; j++)
      #pragma unroll
      for (int r = 0; r < 4; r++) {
        size_t row = (size_t)bm * 128 + wr + i * 16 + quad * 4 + r;
        size_t col = (size_t)bn * 128 + wc + j * 16 + m16;
        float v = acc[i][j][r];
        if (OUTF) ((float*)C)[row * N + col] = v;
        else      ((bf16*)C)[row * N + col] = (bf16)v;
      }
}

// ---------------- 256x256 8-wave deep-pipelined GEMM (T2+T3+T4+T5), bf16 out ----------------
// BK=64 split into two K-half half-tiles (256 rows x 32k = 16KB = 2 global_load_lds/thread).
// 4 phases per K-tile; each phase: ds-read A-slice (+B on kh entry) -> stage exactly 1
// half-tile -> s_barrier -> setprio(1) 16x MFMA setprio(0) -> counted vmcnt(8) on even
// phases -> s_barrier.  Double-buffered LDS; a half-tile region's last LDS read is >=1
// phase before its restage issue, and every half-tile is vmcnt-drained >=1 phase before
// its first read (verified for steady state, prologue, and the peeled last two tiles).
__global__ __launch_bounds__(512) void gemm256_kernel(const bf16* __restrict__ A,
                                                      const bf16* __restrict__ B,
                                                      bf16* __restrict__ C,
                                                      int M, int N, int K) {
  __shared__ bf16 As[4 * 8192];   // [buf*2+kh][256 rows][32 k]
  __shared__ bf16 Bs[4 * 8192];
  int t = threadIdx.x;
  int lane = t & 63, wv = t >> 6;
  int m16 = lane & 15, quad = lane >> 4;
  int wr = wv >> 2, wc = wv & 3;                 // 2 x 4 wave grid, per-wave C = 128x64
  int bn = blockIdx.x, bm = blockIdx.y;
  const bf16* Ab = A + (size_t)bm * 256 * K;
  const bf16* Bb = B + (size_t)bn * 256 * K;
  // per-lane pre-swizzled global source offsets for the two 16B chunks of a half-tile:
  // LDS chunk s (linear) holds global k-chunk (s&3)^((row>>1)&3) of row s>>2.
  int s1i = 512 + t;
  int r0 = t >> 2, r1 = s1i >> 2;
  int soff0 = r0 * K + (((t & 3) ^ ((r0 >> 1) & 3)) * 8);
  int soff1 = r1 * K + (((s1i & 3) ^ ((r1 >> 1) & 3)) * 8);
  // read-side swizzle (lane-constant: frag row = 16*frag + m16)
  int swz8 = (quad ^ ((m16 >> 1) & 3)) * 8;
  f32x4 acc[8][4] = {};
  bf16x8 bq[4];

#define STG(LDSP, GB, KOFF, BK) { \
    gl_lds16((GB) + (KOFF) + soff0, (LDSP) + (BK) * 8192 + wv * 512); \
    gl_lds16((GB) + (KOFF) + soff1, (LDSP) + (BK) * 8192 + 4096 + wv * 512); }

#define LDB4(BK) { _Pragma("unroll") for (int j = 0; j < 4; j++) { \
    int row = wc * 64 + j * 16 + m16; \
    bq[j] = *(const bf16x8*)(&Bs[(BK) * 8192 + row * 32 + swz8]); } }

#define VM8 asm volatile("s_waitcnt vmcnt(8)" ::: "memory");
#define VM4 asm volatile("s_waitcnt vmcnt(4)" ::: "memory");
#define VM0 asm volatile("s_waitcnt vmcnt(0)" ::: "memory");

#define PHASE(BK, ASL, STAGE_STMT, VM_STMT) { \
    bf16x8 af[4]; \
    _Pragma("unroll") for (int i = 0; i < 4; i++) { \
      int row = wr * 128 + (ASL) * 64 + i * 16 + m16; \
      af[i] = *(const bf16x8*)(&As[(BK) * 8192 + row * 32 + swz8]); } \
    STAGE_STMT \
    __builtin_amdgcn_s_barrier(); \
    __builtin_amdgcn_s_setprio(1); \
    _Pragma("unroll") for (int i = 0; i < 4; i++) { \
      _Pragma("unroll") for (int j = 0; j < 4; j++) { \
        acc[(ASL) * 4 + i][j] = \
          __builtin_amdgcn_mfma_f32_16x16x32_bf16(af[i], bq[j], acc[(ASL) * 4 + i][j], 0, 0, 0); } } \
    __builtin_amdgcn_s_setprio(0); \
    VM_STMT \
    __builtin_amdgcn_s_barrier(); }

// one full-rate K-tile: stages A1/B1(t+1) in ph1/ph2 and A0/B0(t+2) in ph3/ph4
#define TILE_FULL(BUF, T) { \
    LDB4((BUF) * 2 + 0); \
    PHASE((BUF) * 2 + 0, 0, STG(As, Ab, ((T) + 1) * 64 + 32, ((BUF) ^ 1) * 2 + 1), ) \
    PHASE((BUF) * 2 + 0, 1, STG(Bs, Bb, ((T) + 1) * 64 + 32, ((BUF) ^ 1) * 2 + 1), VM8) \
    LDB4((BUF) * 2 + 1); \
    PHASE((BUF) * 2 + 1, 0, STG(As, Ab, ((T) + 2) * 64,      (BUF) * 2 + 0), ) \
    PHASE((BUF) * 2 + 1, 1, STG(Bs, Bb, ((T) + 2) * 64,      (BUF) * 2 + 0), VM8) }

  // prologue: tiles 0 (both halves) + tile 1 (kh0); oldest-first matches deadline order
  STG(As, Ab, 0, 0)
  STG(Bs, Bb, 0, 0)
  STG(As, Ab, 32, 1)
  STG(Bs, Bb, 32, 1)
  STG(As, Ab, 64, 2)
  STG(Bs, Bb, 64, 2)
  VM8                                  // drains A0(0), B0(0); leaves 4 half-tiles in flight
  __builtin_amdgcn_s_barrier();

  int nt = K >> 6;                     // K-tiles (K % 128 == 0, nt even, nt >= 4)
  for (int tk = 0; tk < nt - 2; tk += 2) {
    TILE_FULL(0, tk)
    TILE_FULL(1, tk + 1)
  }
  // peeled tile nt-2 (buf 0): stage only A1/B1(nt-1); drain schedule 8 -> 4
  LDB4(0);
  PHASE(0, 0, STG(As, Ab, (nt - 1) * 64 + 32, 3), )
  PHASE(0, 1, STG(Bs, Bb, (nt - 1) * 64 + 32, 3), VM8)
  LDB4(1);
  PHASE(1, 0, , )
  PHASE(1, 1, , VM4)
  // peeled tile nt-1 (buf 1): no staging; drain remaining before kh1 reads
  LDB4(2);
  PHASE(2, 0, , )
  PHASE(2, 1, , VM0)
  LDB4(3);
  PHASE(3, 0, , )
  PHASE(3, 1, , )

#undef TILE_FULL
#undef PHASE
#undef LDB4
#undef STG
#undef VM8
#undef VM4
#undef VM0

  #pragma unroll
  for (int fi = 0; fi < 8; fi++)
    #pragma unroll
    for (int j = 0; j < 4; j++)
      #pragma unroll
      for (int r = 0; r < 4; r++) {
        size_t row = (size_t)bm * 256 + wr * 128 + fi * 16 + quad * 4 + r;
        size_t col = (size_t)bn * 256 + wc * 64 + j * 16 + m16;
        C[row * N + col] = (bf16)acc[fi][j][r];
      }
}

// ---------------- attention: one block per (bw,h), 8 waves; RoPE fused; causal skip ----------------
// q-tile index qi: only score tiles 0..qi+1 are (partially) visible; only the
// diagonal tile tl==qi+1 needs masking, with the position-independent pattern
// m16 > quad*4+r. Wave balance: qi = {wv, 15-wv, 16+wv, 31-wv} -> 70 tile-units
// per wave for every wv. All guards are wave-uniform -> s_cbranch, and the
// score array s[33] keeps static indexing (no scratch spill).
__global__ __launch_bounds__(512) void attn_kernel(const bf16* __restrict__ qkv,
                                                   const bf16* __restrict__ pmbf,
                                                   const float2* __restrict__ tab,
                                                   bf16* __restrict__ ob) {
  __shared__ bf16 Ks[528 * 72];          // K rows (rope'd), padded stride 72
  __shared__ bf16 Vt[64 * 536 + 16];     // V transposed [d][j], stride 536, zero-padded tail
  __shared__ bf16 Pb[8 * 16 * 40];       // per-wave P staging, stride 40
  int bh = blockIdx.x;
  int bw = bh >> 4, h = bh & 15;
  int seg = bw & 7;
  int t = threadIdx.x;
  int wv = t >> 6, lane = t & 63;
  int m16 = lane & 15, quad = lane >> 4;
  const bf16* qk_base = qkv + (size_t)bw * 512 * 3072 + h * 64;  // row s at +s*3072; K +1024; V +2048
  // stage K rows (pm rows 0..15 unroped, seq rows 16..527 roped at global pos)
  for (int ch = t; ch < 4224; ch += 512) {
    int row = ch >> 3, d0 = (ch & 7) * 8;
    bf16 tmp[8];
    if (row < 16) {
      *(uint4*)tmp = *(const uint4*)(pmbf + ((size_t)h * 16 + row) * 64 + d0);
    } else {
      int s = row - 16;
      *(uint4*)tmp = *(const uint4*)(qk_base + (size_t)s * 3072 + 1024 + d0);
      int pos = seg * 512 + s;
      const float2* tb = tab + pos * 32 + (d0 >> 1);
      #pragma unroll
      for (int p = 0; p < 4; p++) {
        float2 cs = tb[p];
        float x0 = (float)tmp[2 * p], x1 = (float)tmp[2 * p + 1];
        tmp[2 * p]     = (bf16)(x0 * cs.x - x1 * cs.y);
        tmp[2 * p + 1] = (bf16)(x1 * cs.x + x0 * cs.y);
      }
    }
    *(uint4*)(&Ks[row * 72 + d0]) = *(uint4*)tmp;
  }
  // stage V transposed (no rope)
  for (int ch = t; ch < 4224; ch += 512) {
    int row = ch >> 3, d0 = (ch & 7) * 8;
    bf16 tmp[8];
    if (row < 16) *(uint4*)tmp = *(const uint4*)(pmbf + ((size_t)(16 + h) * 16 + row) * 64 + d0);
    else          *(uint4*)tmp = *(const uint4*)(qk_base + (size_t)(row - 16) * 3072 + 2048 + d0);
    #pragma unroll
    for (int i = 0; i < 8; i++) Vt[(d0 + i) * 536 + row] = tmp[i];
  }
  // zero-pad Vt cols 528..535 and the tail so ragged chunks read finite zeros
  if (t < 512) { int r = t >> 3, cc = 528 + (t & 7); Vt[r * 536 + cc] = (bf16)0.f; }
  if (t < 16) Vt[64 * 536 + t] = (bf16)0.f;
  __syncthreads();

  bf16* myP = &Pb[wv * 16 * 40];
  for (int pass = 0; pass < 4; pass++) {
    int qi = (pass == 0) ? wv : (pass == 1) ? 15 - wv : (pass == 2) ? 16 + wv : 31 - wv;
    int q0 = qi * 16;
    int ntl = qi + 2;                       // visible score tiles: 0..qi+1
    int qrow = q0 + m16;
    int pos = seg * 512 + qrow;
    const bf16* qp = qk_base + (size_t)qrow * 3072;
    // load Q frags + rope + 1/8 scale in registers
    bf16 qr0[8], qr1[8];
    *(uint4*)qr0 = *(const uint4*)(qp + quad * 8);
    *(uint4*)qr1 = *(const uint4*)(qp + 32 + quad * 8);
    {
      const float2* tb0 = tab + pos * 32 + quad * 4;
      const float2* tb1 = tb0 + 16;
      #pragma unroll
      for (int p = 0; p < 4; p++) {
        float2 c0 = tb0[p], c1 = tb1[p];
        float a0 = (float)qr0[2 * p], a1 = (float)qr0[2 * p + 1];
        qr0[2 * p]     = (bf16)((a0 * c0.x - a1 * c0.y) * 0.125f);
        qr0[2 * p + 1] = (bf16)((a1 * c0.x + a0 * c0.y) * 0.125f);
        float b0 = (float)qr1[2 * p], b1 = (float)qr1[2 * p + 1];
        qr1[2 * p]     = (bf16)((b0 * c1.x - b1 * c1.y) * 0.125f);
        qr1[2 * p + 1] = (bf16)((b1 * c1.x + b0 * c1.y) * 0.125f);
      }
    }
    bf16x8 qf0 = *(bf16x8*)qr0;
    bf16x8 qf1 = *(bf16x8*)qr1;
    f32x4 s[33];
    #pragma unroll
    for (int tl = 0; tl < 33; tl++) {
      if (tl < ntl) {                       // wave-uniform guard
        f32x4 acc = {0.f, 0.f, 0.f, 0.f};
        bf16x8 b0 = *(const bf16x8*)(&Ks[(tl * 16 + m16) * 72 + quad * 8]);
        bf16x8 b1 = *(const bf16x8*)(&Ks[(tl * 16 + m16) * 72 + 32 + quad * 8]);
        acc = __builtin_amdgcn_mfma_f32_16x16x32_bf16(qf0, b0, acc, 0, 0, 0);
        acc = __builtin_amdgcn_mfma_f32_16x16x32_bf16(qf1, b1, acc, 0, 0, 0);
        if (tl == qi + 1) {                 // diagonal tile: mask m16 > quad*4+r
          #pragma unroll
          for (int r = 0; r < 4; r++)
            if (m16 > quad * 4 + r) acc[r] = -1e30f;
        }
        s[tl] = acc;
      }
    }
    // softmax over visible tiles + 16 lanes of the column group
    float lrow[4];
    #pragma unroll
    for (int r = 0; r < 4; r++) {
      float mx = s[0][r];
      #pragma unroll
      for (int tl = 1; tl < 33; tl++) if (tl < ntl) mx = fmaxf(mx, s[tl][r]);
      mx = fmaxf(mx, __shfl_xor(mx, 1, 64));
      mx = fmaxf(mx, __shfl_xor(mx, 2, 64));
      mx = fmaxf(mx, __shfl_xor(mx, 4, 64));
      mx = fmaxf(mx, __shfl_xor(mx, 8, 64));
      float sum = 0.f;
      #pragma unroll
      for (int tl = 0; tl < 33; tl++) {
        if (tl < ntl) {
          float p = exp2f((s[tl][r] - mx) * LOG2E);
          s[tl][r] = p;
          sum += p;
        }
      }
      sum += __shfl_xor(sum, 1, 64);
      sum += __shfl_xor(sum, 2, 64);
      sum += __shfl_xor(sum, 4, 64);
      sum += __shfl_xor(sum, 8, 64);
      lrow[r] = sum;
    }
    // PV over visible chunks of 32 kv (ragged tail zero-filled)
    f32x4 o[4] = {};
    #pragma unroll
    for (int c = 0; c < 17; c++) {
      if (2 * c < ntl) {                    // wave-uniform guard
        #pragma unroll
        for (int half = 0; half < 2; half++) {
          int tl = 2 * c + half;
          #pragma unroll
          for (int r = 0; r < 4; r++) {
            float pv = (tl < ntl) ? s[tl][r] : 0.f;
            myP[(quad * 4 + r) * 40 + half * 16 + m16] = (bf16)pv;
          }
        }
        asm volatile("s_waitcnt lgkmcnt(0)" ::: "memory");   // wave-local: writes visible
        bf16x8 pf = *(const bf16x8*)(&myP[m16 * 40 + quad * 8]);
        #pragma unroll
        for (int dt = 0; dt < 4; dt++) {
          bf16x8 vf = *(const bf16x8*)(&Vt[(dt * 16 + m16) * 536 + c * 32 + quad * 8]);
          o[dt] = __builtin_amdgcn_mfma_f32_16x16x32_bf16(pf, vf, o[dt], 0, 0, 0);
        }
        asm volatile("s_waitcnt lgkmcnt(0)" ::: "memory");   // reads done before next overwrite
      }
    }
    // normalize + write to [8192][1024] merged layout
    float invl[4];
    #pragma unroll
    for (int r = 0; r < 4; r++) invl[r] = 1.0f / lrow[r];
    #pragma unroll
    for (int dt = 0; dt < 4; dt++)
      #pragma unroll
      for (int r = 0; r < 4; r++) {
        size_t row = (size_t)bw * 512 + q0 + quad * 4 + r;
        ob[row * 1024 + h * 64 + dt * 16 + m16] = (bf16)(o[dt][r] * invl[r]);
      }
  }
}

// ---------------- launch ----------------
extern "C" void kernel_launch(void* const* d_in, const int* in_sizes, int n_in,
                              void* d_out, int out_size, void* d_ws, size_t ws_size,
                              hipStream_t stream) {
  const float* seq  = (const float*)d_in[0];
  const float* g    = (const float*)d_in[1];
  const float* wqkv = (const float*)d_in[2];
  const float* wout = (const float*)d_in[3];
  const float* pm   = (const float*)d_in[4];
  float* out = (float*)d_out;
  char* ws = (char*)d_ws;
  bf16*   wqkv_bf = (bf16*)(ws);                  //  6,291,456
  bf16*   wout_bf = (bf16*)(ws + 6291456);        //  2,097,152
  bf16*   pm_bf   = (bf16*)(ws + 8388608);        //     65,536
  float2* tab     = (float2*)(ws + 8454144);      //  1,048,576 (4096 x 32 cos/sin)
  bf16*   x_bf    = (bf16*)(ws + 9502720);        // 16,777,216 (RMSNorm out, reused as attn out)
  bf16*   qkv_bf  = (bf16*)(ws + 26279936);       // 50,331,648 -> 76,611,584 total

  cast3_kernel<<<4640, 256, 0, stream>>>(wqkv, 786432, wqkv_bf,
                                         wout, 262144, wout_bf,
                                         pm, 8192, pm_bf,
                                         tab, 131072);
  rmsnorm_kernel<<<8192, 256, 0, stream>>>(seq, g, x_bf);
  gemm256_kernel<<<dim3(12, 32), 512, 0, stream>>>(x_bf, wqkv_bf, qkv_bf, 8192, 3072, 1024);
  attn_kernel<<<256, 512, 0, stream>>>(qkv_bf, pm_bf, tab, x_bf);
  gemm_bt_kernel<1><<<dim3(8, 64), 256, 0, stream>>>(x_bf, wout_bf, out, 8192, 1024, 1024);
}